// Round 2
// baseline (11055.366 us; speedup 1.0000x reference)
//
#include <hip/hip_runtime.h>
#include <math.h>

#define NMC    32768
#define TSTEPS 1024
#define NPB    64            // paths per block (one per lane)
#define NBLK   (NMC / NPB)   // 512 blocks
#define NW     8             // waves per block: (2 MLPs) x (4 j-quarters)

// Force a pointer into SGPRs so uniform indexing produces s_load (scalar) weight reads.
__device__ __forceinline__ const float* upf(const float* p) {
  unsigned long long v = (unsigned long long)p;
  unsigned lo = __builtin_amdgcn_readfirstlane((unsigned)v);
  unsigned hi = __builtin_amdgcn_readfirstlane((unsigned)(v >> 32));
  return (const float*)(((unsigned long long)hi << 32) | lo);
}

__device__ __forceinline__ float fsilu(float x) {
  // x * sigmoid(x) = x / (1 + e^-x)
  return __fdividef(x, 1.0f + __expf(-x));
}

__global__ __launch_bounds__(64) void init_out(float* __restrict__ out,
                                               const float* __restrict__ lso_p) {
  // nll = lso + 0.5/sigma^2 * mean((y-U)^2); main kernel atomically adds the 2nd term
  if (threadIdx.x == 0) *out = *lso_p;
}

__global__ __launch_bounds__(512) void sde_kernel(
    const float* __restrict__ X_seq, const float* __restrict__ y_seq,
    const float* __restrict__ kappa_p, const float* __restrict__ a_p,
    const float* __restrict__ b0_p, const float* __restrict__ b1_p,
    const float* __restrict__ b2_p, const float* __restrict__ S_p,
    const float* __restrict__ lso_p,
    const float* __restrict__ dW1, const float* __restrict__ db1,
    const float* __restrict__ dW2, const float* __restrict__ db2,
    const float* __restrict__ dW3, const float* __restrict__ db3,
    const float* __restrict__ gW1, const float* __restrict__ gb1,
    const float* __restrict__ gW2, const float* __restrict__ gb2,
    const float* __restrict__ gW3, const float* __restrict__ gb3,
    const float* __restrict__ xi,
    const int* __restrict__ i0_p, const int* __restrict__ dt_p,
    float* __restrict__ out)
{
  // h1T[mlp][k][lane]: lane-contiguous -> 2-way bank alias only (free, m136)
  __shared__ float h1T[2][64][NPB];     // 32 KB
  __shared__ float partials[NW][NPB];   // 2 KB

  const int tid  = threadIdx.x;
  const int lane = tid & 63;
  const int w    = __builtin_amdgcn_readfirstlane(tid >> 6); // wave id 0..7 (uniform)
  const int m    = w >> 2;  // 0 = drift MLP, 1 = g MLP
  const int h    = w & 3;   // j-quarter (16 outputs per wave)
  const int path = blockIdx.x * NPB + lane;

  const float* W1 = upf(m ? gW1 : dW1);
  const float* B1 = upf(m ? gb1 : db1);
  const float* W2 = upf(m ? gW2 : dW2);
  const float* B2 = upf(m ? gb2 : db2);
  const float* W3 = upf(m ? gW3 : dW3);

  const float kappa = *kappa_p;
  const float a0 = a_p[0], a1 = a_p[1], a2 = a_p[2];
  const float b0 = *b0_p, b1c = *b1_p, b2c = *b2_p, S = *S_p, lso = *lso_p;
  const int   i0 = *i0_p;
  const float dtf  = (float)(*dt_p);
  const float sqdt = sqrtf(dtf);
  const float db3v = db3[0], gb3v = gb3[0];
  const float two_pi = 6.28318530717958647692f;

  // z0 = logit(clip(y_seq[i0-1]))
  float y0 = y_seq[i0 - 1];
  y0 = fminf(fmaxf(y0, 1e-4f), 1.0f - 1e-4f);
  float z = logf(y0 / (1.0f - y0));
  float nacc = 0.0f;

  const float* xip = xi + path;

  // 1-step software pipeline on the cold-HBM xi load (~900 cy latency):
  // xik for step t is loaded during step t-1 and travels across the barriers.
  float xik_next = xip[0];

  for (int t = 0; t < TSTEPS; ++t) {
    const float xik = xik_next;
    if (t + 1 < TSTEPS) xik_next = xip[(t + 1) * NMC];   // prefetch, used next iter

    const float tk = (float)(i0 + t);
    const int   xr = (i0 + t) * 3;
    const float x0 = X_seq[xr + 0], x1 = X_seq[xr + 1], x2 = X_seq[xr + 2];

    // ---- layer 1: this wave computes its 16 j's of h1 for its MLP (shared via LDS)
    #pragma unroll
    for (int jj = 0; jj < 16; ++jj) {
      const int j = h * 16 + jj;
      float v = B1[j];
      v = fmaf(z,  W1[0 * 64 + j], v);
      v = fmaf(x0, W1[1 * 64 + j], v);
      v = fmaf(x1, W1[2 * 64 + j], v);
      v = fmaf(x2, W1[3 * 64 + j], v);
      v = fmaf(tk, W1[4 * 64 + j], v);
      h1T[m][j][lane] = fsilu(v);
    }
    __syncthreads();

    // ---- layer 2: acc[16] in registers (static idx only), weights via uniform s_load
    float acc[16];
    #pragma unroll
    for (int jj = 0; jj < 16; ++jj) acc[jj] = B2[h * 16 + jj];
    #pragma unroll 8
    for (int k = 0; k < 64; ++k) {
      const float hk = h1T[m][k][lane];
      const int   wb = k * 64 + h * 16;
      #pragma unroll
      for (int jj = 0; jj < 16; ++jj)
        acc[jj] = fmaf(hk, W2[wb + jj], acc[jj]);
    }

    // ---- layer 3 partial (16 of 64 terms)
    float part = 0.0f;
    #pragma unroll
    for (int jj = 0; jj < 16; ++jj)
      part = fmaf(fsilu(acc[jj]), W3[h * 16 + jj], part);
    partials[w][lane] = part;
    __syncthreads();

    // ---- combine (all waves compute identical z; layer 1 needs z next step)
    const float f    = partials[0][lane] + partials[1][lane]
                     + partials[2][lane] + partials[3][lane] + db3v;
    const float gpre = partials[4][lane] + partials[5][lane]
                     + partials[6][lane] + partials[7][lane] + gb3v;
    // stable softplus + 1e-6
    const float ax = fabsf(gpre);
    const float g  = fmaxf(gpre, 0.0f) + __logf(1.0f + __expf(-ax)) + 1e-6f;

    const float ang = two_pi * tk / S;
    const float mu  = fmaf(x0, a0, fmaf(x1, a1, x2 * a2)) + b0
                      + b1c * __sinf(ang) + b2c * __cosf(ang);
    z = z + (kappa * (mu - z) + f) * dtf + g * sqdt * xik;

    if (w == 0) {
      const float U  = __fdividef(1.0f, 1.0f + __expf(-z));
      const float yt = y_seq[i0 + t];
      const float d  = yt - U;
      nacc = fmaf(d, d, nacc);
    }
  }

  // ---- reduction: wave 0 holds sum_t (y-U)^2 per path
  if (w == 0) {
    #pragma unroll
    for (int off = 32; off; off >>= 1) nacc += __shfl_down(nacc, off, 64);
    if (lane == 0) {
      const float sobs  = __expf(lso) + 1e-8f;
      const float scale = 0.5f / (sobs * sobs) / ((float)TSTEPS * (float)NMC);
      atomicAdd(out, nacc * scale);
    }
  }
}

extern "C" void kernel_launch(void* const* d_in, const int* in_sizes, int n_in,
                              void* d_out, int out_size, void* d_ws, size_t ws_size,
                              hipStream_t stream) {
  const float* X_seq = (const float*)d_in[0];
  const float* y_seq = (const float*)d_in[1];
  const float* kappa = (const float*)d_in[2];
  const float* a     = (const float*)d_in[3];
  const float* b0    = (const float*)d_in[4];
  const float* b1    = (const float*)d_in[5];
  const float* b2    = (const float*)d_in[6];
  const float* S     = (const float*)d_in[7];
  const float* lso   = (const float*)d_in[8];
  const float* dW1   = (const float*)d_in[9];
  const float* db1   = (const float*)d_in[10];
  const float* dW2   = (const float*)d_in[11];
  const float* db2   = (const float*)d_in[12];
  const float* dW3   = (const float*)d_in[13];
  const float* db3   = (const float*)d_in[14];
  const float* gW1   = (const float*)d_in[15];
  const float* gb1   = (const float*)d_in[16];
  const float* gW2   = (const float*)d_in[17];
  const float* gb2   = (const float*)d_in[18];
  const float* gW3   = (const float*)d_in[19];
  const float* gb3   = (const float*)d_in[20];
  const float* xi    = (const float*)d_in[21];
  const int*   i0    = (const int*)d_in[22];
  const int*   dt    = (const int*)d_in[23];
  float* out = (float*)d_out;

  hipLaunchKernelGGL(init_out, dim3(1), dim3(64), 0, stream, out, lso);
  hipLaunchKernelGGL(sde_kernel, dim3(NBLK), dim3(512), 0, stream,
                     X_seq, y_seq, kappa, a, b0, b1, b2, S, lso,
                     dW1, db1, dW2, db2, dW3, db3,
                     gW1, gb1, gW2, gb2, gW3, gb3,
                     xi, i0, dt, out);
}

// Round 6
// 6732.981 us; speedup vs baseline: 1.6420x; 1.6420x over previous
//
#include <hip/hip_runtime.h>
#include <math.h>

#define NMC    32768
#define TSTEPS 1024
#define PPB    32            // paths per block
#define NBLK   (NMC / PPB)   // 1024 blocks
#define TWO_PI 6.28318530717958647692f

// MFMA fragment types (guide §3: short-based bf16 frags, compile-verified on gfx950)
typedef short bf16x8 __attribute__((ext_vector_type(8)));
typedef float f32x4  __attribute__((ext_vector_type(4)));

#define MFMA_B16(A, B, C) (C) = __builtin_amdgcn_mfma_f32_16x16x32_bf16((A), (B), (C), 0, 0, 0)

__device__ __forceinline__ float fsilu(float x) { return __fdividef(x, 1.0f + __expf(-x)); }
__device__ __forceinline__ unsigned fbits(float x){ union{float f;unsigned u;}c; c.f=x; return c.u; }
__device__ __forceinline__ float bitsf(unsigned u){ union{float f;unsigned u;}c; c.u=u; return c.f; }
__device__ __forceinline__ bf16x8 mk8(unsigned a,unsigned b,unsigned c,unsigned d){
  union{unsigned u[4]; bf16x8 s;} z; z.u[0]=a; z.u[1]=b; z.u[2]=c; z.u[3]=d; return z.s;
}

// Truncation split: e = H + M + L + O(2^-27 * |e|), all subtractions exact.
// Packs 8 fp32 -> three bf16x8 frags. Element order is identical for A and B
// fragments, so products align on the same k regardless of HW within-lane order.
__device__ __forceinline__ void split3(const float e[8], bf16x8 &H, bf16x8 &M, bf16x8 &L) {
  unsigned dH[4], dM[4], dL[4];
  #pragma unroll
  for (int v = 0; v < 4; ++v) {
    const float a0 = e[2*v], a1 = e[2*v+1];
    const unsigned uH0 = fbits(a0) & 0xFFFF0000u, uH1 = fbits(a1) & 0xFFFF0000u;
    const float r10 = a0 - bitsf(uH0), r11 = a1 - bitsf(uH1);
    const unsigned uM0 = fbits(r10) & 0xFFFF0000u, uM1 = fbits(r11) & 0xFFFF0000u;
    const float r20 = r10 - bitsf(uM0), r21 = r11 - bitsf(uM1);
    dH[v] = uH1 | (uH0 >> 16);
    dM[v] = uM1 | (uM0 >> 16);
    dL[v] = (fbits(r21) & 0xFFFF0000u) | (fbits(r20) >> 16);
  }
  H = mk8(dH[0],dH[1],dH[2],dH[3]);
  M = mk8(dM[0],dM[1],dM[2],dM[3]);
  L = mk8(dL[0],dL[1],dL[2],dL[3]);
}

__global__ __launch_bounds__(64) void init_out(float* __restrict__ out,
                                               const float* __restrict__ lso_p) {
  if (threadIdx.x == 0) *out = *lso_p;
}

__global__ __launch_bounds__(256) void sde_kernel(
    const float* __restrict__ X_seq, const float* __restrict__ y_seq,
    const float* __restrict__ kappa_p, const float* __restrict__ a_p,
    const float* __restrict__ b0_p, const float* __restrict__ b1_p,
    const float* __restrict__ b2_p, const float* __restrict__ S_p,
    const float* __restrict__ lso_p,
    const float* __restrict__ dW1, const float* __restrict__ db1,
    const float* __restrict__ dW2, const float* __restrict__ db2,
    const float* __restrict__ dW3, const float* __restrict__ db3,
    const float* __restrict__ gW1, const float* __restrict__ gb1,
    const float* __restrict__ gW2, const float* __restrict__ gb2,
    const float* __restrict__ gW3, const float* __restrict__ gb3,
    const float* __restrict__ xi,
    const int* __restrict__ i0_p, const int* __restrict__ dt_p,
    float* __restrict__ out)
{
  __shared__ __align__(16) float preLDS[2][64];  // pre[k] per MLP, lane=k layout
  __shared__ float part[2][PPB];                 // per-path layer-3 sums (f, g-pre)

  const int tid    = threadIdx.x;
  const int l      = tid & 63;
  const int lane15 = l & 15;            // A-row / B-col / C-col index
  const int lg     = l >> 4;            // 0..3 (k-group / C-row group)
  const int w      = __builtin_amdgcn_readfirstlane(tid >> 6); // 0..3
  const int m      = w >> 1;            // 0 = drift MLP, 1 = g MLP
  const int pt     = w & 1;             // path-tile within block (16 paths)
  const int path_l = pt * 16 + lane15;  // 0..31 within block
  const int gpath  = blockIdx.x * PPB + path_l;

  const float* W1 = m ? gW1 : dW1;
  const float* B1 = m ? gb1 : db1;
  const float* W2 = m ? gW2 : dW2;
  const float* B2 = m ? gb2 : db2;
  const float* W3 = m ? gW3 : dW3;

  const float kappa = *kappa_p;
  const float a0 = a_p[0], a1 = a_p[1], a2 = a_p[2];
  const float b0 = *b0_p, b1c = *b1_p, b2c = *b2_p, S = *S_p, lso = *lso_p;
  const int   i0 = *i0_p;
  const float dtf  = (float)(*dt_p);
  const float sqdt = sqrtf(dtf);
  const float db3v = db3[0], gb3v = gb3[0];

  // ---- loop-invariant register state ------------------------------------
  // lane=k layout for the pre[] computation (pt==0 waves use these)
  const float b1v  = B1[l];
  const float w1r1 = W1[1*64 + l], w1r2 = W1[2*64 + l];
  const float w1r3 = W1[3*64 + l], w1r4 = W1[4*64 + l];

  // W1 row 0 (z coefficient) in A-fragment arrangement: k = c*32 + lg*8 + q
  float w1z[2][8];
  #pragma unroll
  for (int c = 0; c < 2; ++c)
    #pragma unroll
    for (int q = 0; q < 8; ++q)
      w1z[c][q] = W1[c*32 + lg*8 + q];

  // per-lane j-indexed constants: j = jt*16 + lane15
  float b2v[4], w3v[4];
  #pragma unroll
  for (int jt = 0; jt < 4; ++jt) {
    b2v[jt] = B2[jt*16 + lane15];
    w3v[jt] = W3[jt*16 + lane15];
  }

  // B-fragments of W2 (k x j), split 3-ways; loop-invariant, held in VGPRs.
  // B element: k = c*32 + lg*8 + (2v+b), j = jt*16 + lane15
  bf16x8 bH[2][4], bM[2][4], bL[2][4];
  #pragma unroll
  for (int c = 0; c < 2; ++c)
    #pragma unroll
    for (int jt = 0; jt < 4; ++jt) {
      float e[8];
      #pragma unroll
      for (int q = 0; q < 8; ++q)
        e[q] = W2[(c*32 + lg*8 + q)*64 + jt*16 + lane15];
      split3(e, bH[c][jt], bM[c][jt], bL[c][jt]);
    }

  // ---- state ------------------------------------------------------------
  float y0 = y_seq[i0 - 1];
  y0 = fminf(fmaxf(y0, 1e-4f), 1.0f - 1e-4f);
  float z = logf(y0 / (1.0f - y0));   // lane l tracks path pt*16+lane15 (replicated over lg)
  float nacc = 0.0f;

  // preloaded per-step inputs (prefetched one step ahead inside the loop)
  float x0 = X_seq[i0*3 + 0], x1 = X_seq[i0*3 + 1], x2 = X_seq[i0*3 + 2];
  float yk  = y_seq[i0];
  float xik = xi[gpath];

  #pragma unroll 1
  for (int t = 0; t < TSTEPS; ++t) {
    const float tk = (float)(i0 + t);

    // ---- pre[k] = b1 + x@W1[1:4] + t*W1[4]  (lane=k, one wave per MLP)
    if (pt == 0) {
      const float pv = fmaf(tk, w1r4, fmaf(x2, w1r3, fmaf(x1, w1r2, fmaf(x0, w1r1, b1v))));
      preLDS[m][l] = pv;
    }
    __syncthreads();  // pre ready; prev-step part[] fully consumed

    // ---- prefetch next-step globals (overlap with compute until barrier 2)
    const int tn = (t + 1 < TSTEPS) ? t + 1 : t;
    const float xn0 = X_seq[(i0+tn)*3 + 0];
    const float xn1 = X_seq[(i0+tn)*3 + 1];
    const float xn2 = X_seq[(i0+tn)*3 + 2];
    const float yn  = y_seq[i0 + tn];
    const float xin = xi[tn*NMC + gpath];

    // ---- layer 1 + A-fragment build (each wave builds exactly what it consumes)
    bf16x8 aH[2], aM[2], aL[2];
    #pragma unroll
    for (int c = 0; c < 2; ++c) {
      const f32x4 p0 = *reinterpret_cast<const f32x4*>(&preLDS[m][c*32 + lg*8 + 0]);
      const f32x4 p1 = *reinterpret_cast<const f32x4*>(&preLDS[m][c*32 + lg*8 + 4]);
      float e[8];
      e[0] = fsilu(fmaf(z, w1z[c][0], p0[0]));
      e[1] = fsilu(fmaf(z, w1z[c][1], p0[1]));
      e[2] = fsilu(fmaf(z, w1z[c][2], p0[2]));
      e[3] = fsilu(fmaf(z, w1z[c][3], p0[3]));
      e[4] = fsilu(fmaf(z, w1z[c][4], p1[0]));
      e[5] = fsilu(fmaf(z, w1z[c][5], p1[1]));
      e[6] = fsilu(fmaf(z, w1z[c][6], p1[2]));
      e[7] = fsilu(fmaf(z, w1z[c][7], p1[3]));
      split3(e, aH[c], aM[c], aL[c]);
    }

    // ---- layer 2 on the matrix pipe: C = A*W2 + b2, 6-product split-bf16
    f32x4 acc[4];
    #pragma unroll
    for (int jt = 0; jt < 4; ++jt) {
      acc[jt][0] = b2v[jt]; acc[jt][1] = b2v[jt];
      acc[jt][2] = b2v[jt]; acc[jt][3] = b2v[jt];
    }
    #pragma unroll
    for (int c = 0; c < 2; ++c) {
      #pragma unroll
      for (int jt = 0; jt < 4; ++jt) {
        MFMA_B16(aH[c], bH[c][jt], acc[jt]);   // H*H
        MFMA_B16(aH[c], bM[c][jt], acc[jt]);   // H*M
        MFMA_B16(aM[c], bH[c][jt], acc[jt]);   // M*H
        MFMA_B16(aH[c], bL[c][jt], acc[jt]);   // H*L
        MFMA_B16(aL[c], bH[c][jt], acc[jt]);   // L*H
        MFMA_B16(aM[c], bM[c][jt], acc[jt]);   // M*M
      }
    }

    // ---- layer 3: per-path sums; C elem (row = pt*16 + lg*4 + r, col j = jt*16+lane15)
    float s0 = 0.0f, s1 = 0.0f, s2 = 0.0f, s3 = 0.0f;
    #pragma unroll
    for (int jt = 0; jt < 4; ++jt) {
      s0 = fmaf(fsilu(acc[jt][0]), w3v[jt], s0);
      s1 = fmaf(fsilu(acc[jt][1]), w3v[jt], s1);
      s2 = fmaf(fsilu(acc[jt][2]), w3v[jt], s2);
      s3 = fmaf(fsilu(acc[jt][3]), w3v[jt], s3);
    }
    // reduce over the 16 lanes (j within tile) of each lane-group
    #pragma unroll
    for (int off = 1; off < 16; off <<= 1) {
      s0 += __shfl_xor(s0, off, 64);
      s1 += __shfl_xor(s1, off, 64);
      s2 += __shfl_xor(s2, off, 64);
      s3 += __shfl_xor(s3, off, 64);
    }
    // lanes with lane15 < 4 publish path (pt*16 + lg*4 + lane15)
    const float sv = lane15 == 0 ? s0 : lane15 == 1 ? s1 : lane15 == 2 ? s2 : s3;
    if (lane15 < 4) part[m][pt*16 + lg*4 + lane15] = sv;
    __syncthreads();  // part ready

    // ---- combine: every wave updates z for its 16 paths (replicated across lg)
    const float f  = part[0][path_l] + db3v;
    const float gp = part[1][path_l] + gb3v;
    const float ax = fabsf(gp);
    const float g  = fmaxf(gp, 0.0f) + __logf(1.0f + __expf(-ax)) + 1e-6f;

    const float ang = TWO_PI * tk / S;
    const float mu  = fmaf(x0, a0, fmaf(x1, a1, x2 * a2)) + b0
                      + b1c * __sinf(ang) + b2c * __cosf(ang);
    z = z + (kappa * (mu - z) + f) * dtf + g * sqdt * xik;

    if (m == 0 && lg == 0) {
      const float U = __fdividef(1.0f, 1.0f + __expf(-z));
      const float d = yk - U;
      nacc = fmaf(d, d, nacc);
    }

    // rotate prefetched inputs
    x0 = xn0; x1 = xn1; x2 = xn2; yk = yn; xik = xin;
  }

  // ---- nll reduction: nacc lives in lanes 0..15 of m==0 waves (zero elsewhere)
  if (m == 0) {
    float v = nacc;
    #pragma unroll
    for (int off = 1; off < 64; off <<= 1) v += __shfl_xor(v, off, 64);
    if (l == 0) {
      const float sobs  = __expf(lso) + 1e-8f;
      const float scale = 0.5f / (sobs * sobs) / ((float)TSTEPS * (float)NMC);
      atomicAdd(out, v * scale);
    }
  }
}

extern "C" void kernel_launch(void* const* d_in, const int* in_sizes, int n_in,
                              void* d_out, int out_size, void* d_ws, size_t ws_size,
                              hipStream_t stream) {
  const float* X_seq = (const float*)d_in[0];
  const float* y_seq = (const float*)d_in[1];
  const float* kappa = (const float*)d_in[2];
  const float* a     = (const float*)d_in[3];
  const float* b0    = (const float*)d_in[4];
  const float* b1    = (const float*)d_in[5];
  const float* b2    = (const float*)d_in[6];
  const float* S     = (const float*)d_in[7];
  const float* lso   = (const float*)d_in[8];
  const float* dW1   = (const float*)d_in[9];
  const float* db1   = (const float*)d_in[10];
  const float* dW2   = (const float*)d_in[11];
  const float* db2   = (const float*)d_in[12];
  const float* dW3   = (const float*)d_in[13];
  const float* db3   = (const float*)d_in[14];
  const float* gW1   = (const float*)d_in[15];
  const float* gb1   = (const float*)d_in[16];
  const float* gW2   = (const float*)d_in[17];
  const float* gb2   = (const float*)d_in[18];
  const float* gW3   = (const float*)d_in[19];
  const float* gb3   = (const float*)d_in[20];
  const float* xi    = (const float*)d_in[21];
  const int*   i0    = (const int*)d_in[22];
  const int*   dt    = (const int*)d_in[23];
  float* out = (float*)d_out;

  hipLaunchKernelGGL(init_out, dim3(1), dim3(64), 0, stream, out, lso);
  hipLaunchKernelGGL(sde_kernel, dim3(NBLK), dim3(256), 0, stream,
                     X_seq, y_seq, kappa, a, b0, b1, b2, S, lso,
                     dW1, db1, dW2, db2, dW3, db3,
                     gW1, gb1, gW2, gb2, gW3, gb3,
                     xi, i0, dt, out);
}